// Round 14
// baseline (176.993 us; speedup 1.0000x reference)
//
#include <hip/hip_runtime.h>

// Problem constants: B=32, C=768, H=W=24 -> HW=576
#define B_  32
#define C_  768
#define HW_ 576

#define NCQ 18               // HW_/32 k-chunks (qk)
#define NCP 24               // C_/32 k-chunks (pv)

typedef _Float16 half8 __attribute__((ext_vector_type(8)));
typedef _Float16 half4 __attribute__((ext_vector_type(4)));
typedef float    f32x4 __attribute__((ext_vector_type(4)));

__device__ __forceinline__ void g2l16(const void* g, void* l) {
    __builtin_amdgcn_global_load_lds(
        (const __attribute__((address_space(1))) unsigned int*)g,
        (__attribute__((address_space(3))) unsigned int*)l, 16, 0, 0);
}

#define VM(N) asm volatile("s_waitcnt vmcnt(" #N ")" ::: "memory")

// ---------------------------------------------------------------------------
// prep2: f2 -> kv16 (row-major fp16 staged tiles) + vt (transposed fp16 via
// coalesced LDS transpose). q16 ELIMINATED (qk14 stages A from f1 directly).
// ---------------------------------------------------------------------------
__global__ __launch_bounds__(256) void prep2(const float* __restrict__ f2,
                                             char* __restrict__ kv16,
                                             char* __restrict__ vt,
                                             int b0, int cur, int nkv) {
    __shared__ float Vsh[32 * 201];
    const int bid = blockIdx.x;
    if (bid < nkv) {
        const int bz = bid % cur, u = bid / cur;        // u in [0,216)
        int g   = u * 256 + threadIdx.x;                // [ti][k0][row][x]
        int x   = g & 3;
        int row = (g >> 2) & 127;
        int t3  = g >> 9;                               // ti*18 + k0
        int k0  = t3 % 18;
        int ti  = t3 / 18;
        int kc  = x ^ ((row >> 1) & 3);
        size_t src = ((size_t)(b0 + bz) * C_ + ti * 128 + row) * HW_ + k0 * 32 + kc * 8;
        f32x4 c0 = *(const f32x4*)(f2 + src);
        f32x4 c1 = *(const f32x4*)(f2 + src + 4);
        half8 hb;
        #pragma unroll
        for (int e = 0; e < 4; ++e) { hb[e] = (_Float16)c0[e]; hb[4 + e] = (_Float16)c1[e]; }
        size_t dst = ((size_t)(((size_t)bz * 6 + ti) * 18 + k0) << 9) | (g & 511);
        *(half8*)(kv16 + dst * 16) = hb;
    } else {
        int bid2 = bid - nkv;
        const int bz = bid2 % cur, u = bid2 / cur;      // u in [0,72)
        int k0 = u / 3, tj = u % 3;
        int b  = b0 + bz;
        int t  = threadIdx.x;
        #pragma unroll
        for (int p = 0; p < 6; ++p) {
            int fidx = p * 256 + t;
            int dd = fidx / 48, c4 = fidx % 48;
            f32x4 v = *(const f32x4*)(f2 + ((size_t)b * C_ + k0 * 32 + dd) * HW_ + tj * 192 + c4 * 4);
            #pragma unroll
            for (int e = 0; e < 4; ++e) Vsh[dd * 201 + c4 * 4 + e] = v[e];
        }
        __syncthreads();
        char* ob = vt + ((size_t)(bz * 3 + tj) * NCP + k0) * 12288;
        #pragma unroll
        for (int p = 0; p < 3; ++p) {
            int o = p * 256 + t;
            int x = o & 3, n = o >> 2;
            int kc = x ^ ((n >> 1) & 3);
            half8 h;
            #pragma unroll
            for (int j = 0; j < 8; ++j) h[j] = (_Float16)Vsh[(kc * 8 + j) * 201 + n];
            *(half8*)(ob + o * 16) = h;
        }
    }
}

// ---------------------------------------------------------------------------
// qk14: attn(fp32) = q @ kv^T. Tile 192x192, 8 waves (4Mx2N), BK=32, ring-3.
// SINGLE DELTA vs round-13 qk6: A-operand reg-staged DIRECTLY from f1 fp32
// (load -> cvt -> swizzled ds_write, pv10's proven A-path skeleton); B via
// g2l from kv16 (pv8's per-wave assignment). Same LDS layout, same MFMA
// order, same epilogue -> bit-identical output.
// Per-wave VMEM queue (w<4 / w>=4): B=2/1 g2l per chunk, A=4/2 loads per
// chunk. Steady VM(8)/VM(4) = wait B(c); tails VM(2)/VM(1), VM(0).
// ---------------------------------------------------------------------------
__global__ __launch_bounds__(512, 4) void qk14(const float* __restrict__ f1,
                                               const char* __restrict__ kv16,
                                               float* __restrict__ attn,
                                               float2* __restrict__ part,
                                               int b0, int cur) {
    __shared__ __align__(16) char S[3][24576];   // per slot: A 12KB | B 12KB
    const int wg = blockIdx.x;
    const int bz = wg % cur, u = wg / cur;       // u in [0,16)
    const int ti = u >> 2, tj = u & 3;
    const int t = threadIdx.x, lane = t & 63, w = t >> 6;
    const int rsub = lane >> 2, cb = (lane & 3) * 16;

    // ---- B staging (g2l from kv16): w<4 -> rows {32w,32w+16}; w>=4 -> row 128+16(w-4) ----
    const char *pB0, *pB1 = nullptr;
    int oB0, oB1 = 0;
    {
        auto brow = [&](int l) {             // covers B rows 16l..16l+15
            int gd = tj * 192 + 16 * l + rsub;
            return kv16 + ((size_t)(bz * 6 + (gd >> 7)) * NCQ) * 8192 + (gd & 127) * 64 + cb;
        };
        if (w < 4) {
            pB0 = brow(2 * w);     oB0 = 12288 + (2 * w) * 1024;
            pB1 = brow(2 * w + 1); oB1 = 12288 + (2 * w + 1) * 1024;
        } else {
            pB0 = brow(8 + (w - 4)); oB0 = 12288 + (8 + (w - 4)) * 1024;
        }
    }

    // ---- A reg-staging from f1: slot s: r=s>>2, x=s&3; thread t owns slot t
    // (all) and slot t+512 (t<256; row r+128 has same kc since 64%4==0). ----
    const int r0 = t >> 2, x0 = t & 3;
    const int kc0 = x0 ^ ((r0 >> 1) & 3);
    const float* srcA0 = f1 + ((size_t)(b0 + bz) * C_ + ti * 192 + r0) * HW_ + kc0 * 8;
    const float* srcA1 = srcA0 + (size_t)128 * HW_;     // row r0+128
    const int aw0 = r0 * 64 + x0 * 16;
    const int aw1 = aw0 + 8192;

    const int wr = (w >> 1) * 48, wc = (w & 1) * 96;
    const int r16 = lane & 15, cg = lane >> 4;
    int offA[3], offB[6];
    #pragma unroll
    for (int m = 0; m < 3; ++m) {
        int ra = wr + m * 16 + r16;
        offA[m] = ra * 64 + ((cg ^ ((ra >> 1) & 3)) << 4);
    }
    #pragma unroll
    for (int n = 0; n < 6; ++n) {
        int rb = wc + n * 16 + r16;
        offB[n] = 12288 + rb * 64 + ((cg ^ ((rb >> 1) & 3)) << 4);
    }

    f32x4 acc[3][6] = {};
    f32x4 vaA0, vaA1, vaA2, vaA3;   // named set A
    f32x4 vaB0, vaB1, vaB2, vaB3;   // named set B

#define STG_B(SLOT) do {                                      \
        g2l16(pB0, &S[SLOT][0] + oB0); pB0 += 8192;           \
        if (w < 4) { g2l16(pB1, &S[SLOT][0] + oB1); pB1 += 8192; } \
    } while (0)
#define LD_A(V0, V1, V2, V3) do {                             \
        V0 = *(const f32x4*)srcA0; V1 = *(const f32x4*)(srcA0 + 4); \
        srcA0 += 32;                                          \
        if (w < 4) { V2 = *(const f32x4*)srcA1;               \
                     V3 = *(const f32x4*)(srcA1 + 4); srcA1 += 32; } \
    } while (0)
#define WR_A(SLOT, V0, V1, V2, V3) do {                       \
        half8 h_;                                             \
        _Pragma("unroll")                                     \
        for (int e = 0; e < 4; ++e) { h_[e] = (_Float16)V0[e]; h_[4 + e] = (_Float16)V1[e]; } \
        *(half8*)(&S[SLOT][0] + aw0) = h_;                    \
        if (w < 4) {                                          \
            half8 h2_;                                        \
            _Pragma("unroll")                                 \
            for (int e = 0; e < 4; ++e) { h2_[e] = (_Float16)V2[e]; h2_[4 + e] = (_Float16)V3[e]; } \
            *(half8*)(&S[SLOT][0] + aw1) = h2_;               \
        }                                                     \
    } while (0)
#define QMFMA(SLOT) do {                                      \
        const char* sb_ = &S[SLOT][0];                        \
        half8 a0 = *(const half8*)(sb_ + offA[0]);            \
        half8 a1 = *(const half8*)(sb_ + offA[1]);            \
        half8 a2 = *(const half8*)(sb_ + offA[2]);            \
        __builtin_amdgcn_s_setprio(1);                        \
        _Pragma("unroll")                                     \
        for (int n = 0; n < 6; ++n) {                         \
            half8 bn = *(const half8*)(sb_ + offB[n]);        \
            acc[0][n] = __builtin_amdgcn_mfma_f32_16x16x32_f16(a0, bn, acc[0][n], 0, 0, 0); \
            acc[1][n] = __builtin_amdgcn_mfma_f32_16x16x32_f16(a1, bn, acc[1][n], 0, 0, 0); \
            acc[2][n] = __builtin_amdgcn_mfma_f32_16x16x32_f16(a2, bn, acc[2][n], 0, 0, 0); \
        }                                                     \
        __builtin_amdgcn_s_setprio(0);                        \
    } while (0)
// Phase c: lgkm0+bar | STG_B(c+2) | VM | bar | MFMA(c) | WR_A(c+2, set loaded
// at phase c-1) | LD_A(c+3 -> other set). Sets alternate per phase.
#define QITER(W0,W1,W2,W3, L0,L1,L2,L3) do {                  \
        asm volatile("s_waitcnt lgkmcnt(0)" ::: "memory");    \
        __builtin_amdgcn_s_barrier();                         \
        if (c + 2 < NCQ) STG_B((c + 2) % 3);                  \
        if (c + 2 < NCQ)      { if (w < 4) VM(8); else VM(4); } \
        else if (c + 1 < NCQ) { if (w < 4) VM(2); else VM(1); } \
        else                  { VM(0); }                      \
        __builtin_amdgcn_s_barrier();                         \
        QMFMA(c % 3);                                         \
        if (c + 2 < NCQ) WR_A((c + 2) % 3, W0, W1, W2, W3);   \
        if (c + 3 < NCQ) LD_A(L0, L1, L2, L3);                \
        ++c;                                                  \
    } while (0)

    // prologue: A(0)->slot0, A(1)->slot1 (ds_writes), B(0),B(1) g2l, A(2)->setA
    LD_A(vaA0, vaA1, vaA2, vaA3);
    WR_A(0, vaA0, vaA1, vaA2, vaA3);
    LD_A(vaB0, vaB1, vaB2, vaB3);
    WR_A(1, vaB0, vaB1, vaB2, vaB3);
    STG_B(0); STG_B(1);
    LD_A(vaA0, vaA1, vaA2, vaA3);     // chunk 2

    int c = 0;
    for (int it = 0; it < 9; ++it) {
        QITER(vaA0, vaA1, vaA2, vaA3, vaB0, vaB1, vaB2, vaB3); // even: WR setA, LD setB
        QITER(vaB0, vaB1, vaB2, vaB3, vaA0, vaA1, vaA2, vaA3); // odd:  WR setB, LD setA
    }
#undef QITER
#undef QMFMA
#undef WR_A
#undef LD_A
#undef STG_B

    float* ab = attn + ((size_t)bz * C_ + ti * 192) * C_ + tj * 192;
    const int col = lane & 15, rbase = (lane >> 4) * 4;
    #pragma unroll
    for (int m = 0; m < 3; ++m)
        #pragma unroll
        for (int n = 0; n < 6; ++n)
            #pragma unroll
            for (int rg = 0; rg < 4; ++rg)
                ab[(size_t)(wr + m * 16 + rbase + rg) * C_ + wc + n * 16 + col] = acc[m][n][rg];

    // per-(row, 96-col half) softmax partials; slot = tj*2 + (w&1).
    const int half = w & 1;
    #pragma unroll
    for (int m = 0; m < 3; ++m)
        #pragma unroll
        for (int rg = 0; rg < 4; ++rg) {
            float mx = -1e30f;
            #pragma unroll
            for (int n = 0; n < 6; ++n) mx = fmaxf(mx, acc[m][n][rg]);
            #pragma unroll
            for (int o = 1; o < 16; o <<= 1) mx = fmaxf(mx, __shfl_xor(mx, o));
            float s = 0.f;
            #pragma unroll
            for (int n = 0; n < 6; ++n) s += __expf(acc[m][n][rg] - mx);
            #pragma unroll
            for (int o = 1; o < 16; o <<= 1) s += __shfl_xor(s, o);
            if ((lane & 15) == 0) {
                int row = wr + m * 16 + (lane >> 4) * 4 + rg;
                part[((size_t)bz * C_ + ti * 192 + row) * 8 + tj * 2 + half] =
                    make_float2(mx, s);
            }
        }
}

// ---------------------------------------------------------------------------
// sm_combine: stats[R] = {m, gamma/s} from 8 per-(tile,half) partials per row.
// ---------------------------------------------------------------------------
__global__ __launch_bounds__(256) void sm_combine(const float2* __restrict__ part,
                                                  float2* __restrict__ stats,
                                                  const float* __restrict__ gamma,
                                                  int cur) {
    const int bid = blockIdx.x;
    const int bz = bid % cur, u = bid / cur;     // u in [0,3)
    const int R = bz * C_ + u * 256 + threadIdx.x;
    float2 p[8];
    #pragma unroll
    for (int i = 0; i < 8; ++i) p[i] = part[(size_t)R * 8 + i];
    float m = p[0].x;
    #pragma unroll
    for (int i = 1; i < 8; ++i) m = fmaxf(m, p[i].x);
    float s = 0.f;
    #pragma unroll
    for (int i = 0; i < 8; ++i) s += p[i].y * __expf(p[i].x - m);
    stats[R] = make_float2(m, gamma[0] / s);
}

// ---------------------------------------------------------------------------
// pv10: out = (gamma*P)@V + feat1, softmax fused into A-staging. (round-13
// exact: paired chunks, ring-4 of 20KB slots, depth-1 pair prefetch)
// ---------------------------------------------------------------------------
__global__ __launch_bounds__(512, 4) void pv10(const float* __restrict__ attn,
                                               const char* __restrict__ vt,
                                               const float2* __restrict__ stats,
                                               const float* __restrict__ f1,
                                               float* __restrict__ out,
                                               int b0, int cur) {
    __shared__ __align__(16) char S[4][20480];   // per slot: A 8KB | B 12KB
    const int wg = blockIdx.x;
    const int bz = wg % cur, u = wg / cur;       // u in [0,18)
    const int ti = u / 3, tj = u % 3;
    const int t = threadIdx.x, lane = t & 63, w = t >> 6;
    const int rsub = lane >> 2, cbb = (lane & 3) * 16;

    const int r0 = t >> 3;            // rows 0..63
    const int r1 = 64 + r0;           // rows 64..127
    const int d4 = t & 7;
    const float* srcA0 = attn + ((size_t)bz * C_ + ti * 128 + r0) * C_ + d4 * 4;
    const float* srcA1 = attn + ((size_t)bz * C_ + ti * 128 + r1) * C_ + d4 * 4;
    const float2 ms0 = stats[bz * C_ + ti * 128 + r0];
    const float2 ms1 = stats[bz * C_ + ti * 128 + r1];
    const int aw0 = r0 * 64 + (((d4 >> 1) ^ ((r0 >> 1) & 3)) << 4) + (d4 & 1) * 8;
    const int aw1 = r1 * 64 + (((d4 >> 1) ^ ((r1 >> 1) & 3)) << 4) + (d4 & 1) * 8;

    const char* vbase = vt + ((size_t)(bz * 3 + tj) * NCP) * 12288;
    const char *pB0, *pB1;
    int ob0, ob1;
    if (w < 4) {
        pB0 = vbase + (32 * w + rsub) * 64 + cbb;          ob0 = 8192 + (32 * w) * 64;
        pB1 = vbase + (32 * w + 16 + rsub) * 64 + cbb;     ob1 = 8192 + (32 * w + 16) * 64;
    } else {
        pB0 = vbase + (128 + 16 * (w - 4) + rsub) * 64 + cbb;
        ob0 = 8192 + (128 + 16 * (w - 4)) * 64;
        pB1 = vbase; ob1 = 0;  // unused
    }

    const int wr = (w >> 2) * 64, wc = (w & 3) * 48;
    const int r16 = lane & 15, cg = lane >> 4;
    int offA[4], offB[3];
    #pragma unroll
    for (int m = 0; m < 4; ++m) {
        int ra = wr + m * 16 + r16;
        offA[m] = ra * 64 + ((cg ^ ((ra >> 1) & 3)) << 4);
    }
    #pragma unroll
    for (int n = 0; n < 3; ++n) {
        int rb = wc + n * 16 + r16;
        offB[n] = 8192 + rb * 64 + ((cg ^ ((rb >> 1) & 3)) << 4);
    }

    f32x4 acc[4][3] = {};
    f32x4 vaA0, vaA1;
    f32x4 vaB0, vaB1;

#define STG_B(SLOT) do {                                  \
        g2l16(pB0, &S[SLOT][0] + ob0); pB0 += 12288;      \
        if (w < 4) { g2l16(pB1, &S[SLOT][0] + ob1); pB1 += 12288; } \
    } while (0)
#define LD_A(V0, V1) do { V0 = *(const f32x4*)srcA0; V1 = *(const f32x4*)srcA1; \
                          srcA0 += 32; srcA1 += 32; } while (0)
#define WR_A(SLOT, V0, V1) do {                                        \
        half4 h0, h1;                                                  \
        _Pragma("unroll")                                              \
        for (int e = 0; e < 4; ++e) {                                  \
            h0[e] = (_Float16)(__expf(V0[e] - ms0.x) * ms0.y);         \
            h1[e] = (_Float16)(__expf(V1[e] - ms1.x) * ms1.y);         \
        }                                                              \
        *(half4*)(&S[SLOT][0] + aw0) = h0;                             \
        *(half4*)(&S[SLOT][0] + aw1) = h1;                             \
    } while (0)
#define MFMA_SLOT(SB) do {                                             \
        const char* sb_ = (SB);                                        \
        half8 a_[4], b_[3];                                            \
        _Pragma("unroll")                                              \
        for (int m = 0; m < 4; ++m) a_[m] = *(const half8*)(sb_ + offA[m]); \
        _Pragma("unroll")                                              \
        for (int n = 0; n < 3; ++n) b_[n] = *(const half8*)(sb_ + offB[n]); \
        _Pragma("unroll")                                              \
        for (int m = 0; m < 4; ++m)                                    \
            _Pragma("unroll")                                          \
            for (int n = 0; n < 3; ++n)                                \
                acc[m][n] = __builtin_amdgcn_mfma_f32_16x16x32_f16(a_[m], b_[n], acc[m][n], 0, 0, 0); \
    } while (0)

    LD_A(vaA0, vaA1);
    WR_A(0, vaA0, vaA1);
    LD_A(vaB0, vaB1);
    WR_A(1, vaB0, vaB1);
    STG_B(0); STG_B(1);
    LD_A(vaA0, vaA1);        // chunk 2
    LD_A(vaB0, vaB1);        // chunk 3

    for (int p = 0; p < 12; ++p) {
        const int sa = (2 * p) & 3;
        asm volatile("s_waitcnt lgkmcnt(0)" ::: "memory");
        __builtin_amdgcn_s_barrier();
        if (p < 11) { STG_B((sa + 2) & 3); STG_B((sa + 3) & 3); }
        if (p < 11) { if (w < 4) VM(8); else VM(6); }
        else        { VM(0); }
        __builtin_amdgcn_s_barrier();

        __builtin_amdgcn_s_setprio(1);
        MFMA_SLOT(&S[sa][0]);
        MFMA_SLOT(&S[sa ^ 1][0]);
        __builtin_amdgcn_s_setprio(0);

        if (p < 11) {
            WR_A((sa + 2) & 3, vaA0, vaA1);
            WR_A((sa + 3) & 3, vaB0, vaB1);
            if (p < 10) {
                LD_A(vaA0, vaA1);
                LD_A(vaB0, vaB1);
            }
        }
    }
#undef MFMA_SLOT
#undef WR_A
#undef LD_A
#undef STG_B

    const int b = b0 + bz;
    const float* f1b = f1 + ((size_t)b * C_ + ti * 128) * HW_ + tj * 192;
    float*       ob  = out + ((size_t)b * C_ + ti * 128) * HW_ + tj * 192;
    const int col = lane & 15, rbase = (lane >> 4) * 4;
    #pragma unroll
    for (int m = 0; m < 4; ++m)
        #pragma unroll
        for (int n = 0; n < 3; ++n)
            #pragma unroll
            for (int rg = 0; rg < 4; ++rg) {
                int r2 = wr + m * 16 + rbase + rg;
                int c2 = wc + n * 16 + col;
                ob[(size_t)r2 * HW_ + c2] = acc[m][n][rg] + f1b[(size_t)r2 * HW_ + c2];
            }
}

// ---------------------------------------------------------------------------
extern "C" void kernel_launch(void* const* d_in, const int* in_sizes, int n_in,
                              void* d_out, int out_size, void* d_ws, size_t ws_size,
                              hipStream_t stream) {
    const float* feat1 = (const float*)d_in[0];
    const float* feat2 = (const float*)d_in[1];
    const float* gamma = (const float*)d_in[2];
    float* out = (float*)d_out;

    const size_t SZ_KV   = (size_t)C_ * HW_ * 2;      //   884,736 B/batch
    const size_t SZ_ATTN = (size_t)C_ * C_  * 4;      // 2,359,296 B/batch (fp32)
    const size_t SZ_PART = (size_t)C_ * 8 * 8;        //    49,152 B/batch
    const size_t SZ_ST   = (size_t)C_ * 8;            //     6,144 B/batch
    const size_t per_batch = SZ_ATTN + 2 * SZ_KV + SZ_PART + SZ_ST;

    int nb = (int)(ws_size / per_batch);
    if (nb < 1) nb = 1;
    if (nb > B_) nb = B_;

    char* ws     = (char*)d_ws;
    float* attn  = (float*)ws;
    char* kv16   = ws + (size_t)nb * SZ_ATTN;
    char* vtb    = kv16 + (size_t)nb * SZ_KV;
    float2* part = (float2*)(vtb + (size_t)nb * SZ_KV);
    float2* stats = (float2*)((char*)part + (size_t)nb * SZ_PART);

    for (int b0 = 0; b0 < B_; b0 += nb) {
        int cur = (B_ - b0 < nb) ? (B_ - b0) : nb;
        prep2<<<cur * 288, 256, 0, stream>>>(feat2, kv16, vtb, b0, cur, cur * 216);
        qk14<<<cur * 16, 512, 0, stream>>>(feat1, kv16, attn, part, b0, cur);
        sm_combine<<<cur * 3, 256, 0, stream>>>(part, stats, gamma, cur);
        pv10<<<cur * 18, 512, 0, stream>>>(attn, vtb, stats, feat1, out, b0, cur);
    }
}

// Round 15
// 142.742 us; speedup vs baseline: 1.2399x; 1.2399x over previous
//
#include <hip/hip_runtime.h>

// Problem constants: B=32, C=768, H=W=24 -> HW=576
#define B_  32
#define C_  768
#define HW_ 576

#define NCQ 18               // HW_/32 k-chunks (qk)
#define NCP 24               // C_/32 k-chunks (pv)

typedef _Float16 half8 __attribute__((ext_vector_type(8)));
typedef _Float16 half4 __attribute__((ext_vector_type(4)));
typedef float    f32x4 __attribute__((ext_vector_type(4)));

__device__ __forceinline__ void g2l16(const void* g, void* l) {
    __builtin_amdgcn_global_load_lds(
        (const __attribute__((address_space(1))) unsigned int*)g,
        (__attribute__((address_space(3))) unsigned int*)l, 16, 0, 0);
}

#define VM(N) asm volatile("s_waitcnt vmcnt(" #N ")" ::: "memory")

// attn is stored LINEARIZED chunk-major (pv's staging layout):
//   float index = ((bz*6 + strip)*24 + chunk)*4096 + row_in_strip*32 + col_in_chunk
// where strip = global_row>>7, chunk = global_col>>5. This makes pv's A-read
// a fully sequential 16KB-per-chunk stream (the round-14 experiment proved
// strided tile-gathers run 2.5-4.5x slower than linearized streams).

// ---------------------------------------------------------------------------
// prep_all: feat1/feat2 fp32 -> q16/kv16 (row-major fp16 staged tiles) and
// vt (transposed fp16 tiles via coalesced LDS transpose). (round-13 exact)
// ---------------------------------------------------------------------------
__global__ __launch_bounds__(256) void prep_all(const float* __restrict__ f1,
                                                const float* __restrict__ f2,
                                                char* __restrict__ q16,
                                                char* __restrict__ kv16,
                                                char* __restrict__ vt,
                                                int b0, int cur, int nqk) {
    __shared__ float Vsh[32 * 201];
    const int bid = blockIdx.x;
    if (bid < nqk) {
        const int bz = bid % cur, u = bid / cur;        // u in [0,216)
        int g   = u * 256 + threadIdx.x;                // [ti][k0][row][x]
        int x   = g & 3;
        int row = (g >> 2) & 127;
        int t3  = g >> 9;                               // ti*18 + k0
        int k0  = t3 % 18;
        int ti  = t3 / 18;
        int kc  = x ^ ((row >> 1) & 3);
        size_t src = ((size_t)(b0 + bz) * C_ + ti * 128 + row) * HW_ + k0 * 32 + kc * 8;
        f32x4 a0 = *(const f32x4*)(f1 + src);
        f32x4 a1 = *(const f32x4*)(f1 + src + 4);
        f32x4 c0 = *(const f32x4*)(f2 + src);
        f32x4 c1 = *(const f32x4*)(f2 + src + 4);
        half8 ha, hb;
        #pragma unroll
        for (int e = 0; e < 4; ++e) {
            ha[e] = (_Float16)a0[e]; ha[4 + e] = (_Float16)a1[e];
            hb[e] = (_Float16)c0[e]; hb[4 + e] = (_Float16)c1[e];
        }
        size_t dst = ((size_t)(((size_t)bz * 6 + ti) * 18 + k0) << 9) | (g & 511);
        *(half8*)(q16  + dst * 16) = ha;
        *(half8*)(kv16 + dst * 16) = hb;
    } else {
        int bid2 = bid - nqk;
        const int bz = bid2 % cur, u = bid2 / cur;      // u in [0,72)
        int k0 = u / 3, tj = u % 3;
        int b  = b0 + bz;
        int t  = threadIdx.x;
        #pragma unroll
        for (int p = 0; p < 6; ++p) {
            int fidx = p * 256 + t;
            int dd = fidx / 48, c4 = fidx % 48;
            f32x4 v = *(const f32x4*)(f2 + ((size_t)b * C_ + k0 * 32 + dd) * HW_ + tj * 192 + c4 * 4);
            #pragma unroll
            for (int e = 0; e < 4; ++e) Vsh[dd * 201 + c4 * 4 + e] = v[e];
        }
        __syncthreads();
        char* ob = vt + ((size_t)(bz * 3 + tj) * NCP + k0) * 12288;
        #pragma unroll
        for (int p = 0; p < 3; ++p) {
            int o = p * 256 + t;
            int x = o & 3, n = o >> 2;
            int kc = x ^ ((n >> 1) & 3);
            half8 h;
            #pragma unroll
            for (int j = 0; j < 8; ++j) h[j] = (_Float16)Vsh[(kc * 8 + j) * 201 + n];
            *(half8*)(ob + o * 16) = h;
        }
    }
}

// ---------------------------------------------------------------------------
// qk6: attn = q @ kv^T. Tile 192x192, 8 waves (4Mx2N), BK=32, ring-3,
// depth-2 counted-vmcnt pipeline. SINGLE DELTA vs round-13: epilogue writes
// attn in the LINEARIZED chunk-major layout (same values, same order).
// ---------------------------------------------------------------------------
__global__ __launch_bounds__(512, 4) void qk6(const char* __restrict__ q16,
                                              const char* __restrict__ kv16,
                                              float* __restrict__ attn,
                                              float2* __restrict__ part,
                                              int cur) {
    __shared__ __align__(16) char S[3][24576];
    const int wg = blockIdx.x;
    const int bz = wg % cur, u = wg / cur;   // u in [0,16)
    const int ti = u >> 2, tj = u & 3;
    const int t = threadIdx.x, lane = t & 63, w = t >> 6;
    const int rsub = lane >> 2, cb = (lane & 3) * 16;

    const char *p0, *p1, *p2;
    int o0, o1, o2;
    {
        auto arow = [&](int l) {
            int gr = ti * 192 + 16 * l + rsub;
            return q16 + ((size_t)(bz * 6 + (gr >> 7)) * NCQ) * 8192 + (gr & 127) * 64 + cb;
        };
        auto brow = [&](int l) {
            int gd = tj * 192 + 16 * l + rsub;
            return kv16 + ((size_t)(bz * 6 + (gd >> 7)) * NCQ) * 8192 + (gd & 127) * 64 + cb;
        };
        if (w < 4) {
            p0 = arow(2 * w);     o0 = (2 * w) * 1024;
            p1 = arow(2 * w + 1); o1 = (2 * w + 1) * 1024;
            p2 = brow(8 + w);     o2 = 12288 + (8 + w) * 1024;
        } else {
            int v = w - 4;
            p0 = brow(2 * v);     o0 = 12288 + (2 * v) * 1024;
            p1 = brow(2 * v + 1); o1 = 12288 + (2 * v + 1) * 1024;
            p2 = arow(8 + v);     o2 = (8 + v) * 1024;
        }
    }

    const int wr = (w >> 1) * 48, wc = (w & 1) * 96;
    const int r16 = lane & 15, cg = lane >> 4;
    int offA[3], offB[6];
    #pragma unroll
    for (int m = 0; m < 3; ++m) {
        int ra = wr + m * 16 + r16;
        offA[m] = ra * 64 + ((cg ^ ((ra >> 1) & 3)) << 4);
    }
    #pragma unroll
    for (int n = 0; n < 6; ++n) {
        int rb = wc + n * 16 + r16;
        offB[n] = 12288 + rb * 64 + ((cg ^ ((rb >> 1) & 3)) << 4);
    }

    f32x4 acc[3][6] = {};

#define STG(SLOT) do {                          \
        char* sb_ = &S[SLOT][0];                \
        g2l16(p0, sb_ + o0);                    \
        g2l16(p1, sb_ + o1);                    \
        g2l16(p2, sb_ + o2);                    \
        p0 += 8192; p1 += 8192; p2 += 8192;     \
    } while (0)

    STG(0); STG(1);
    int rd = 0, st = 2;
    for (int c = 0; c < NCQ; ++c) {
        if (c + 2 < NCQ) {
            STG(st); st = (st == 2) ? 0 : st + 1;
            VM(6);
        } else if (c + 2 == NCQ) {
            VM(3);
        } else {
            VM(0);
        }
        __builtin_amdgcn_s_barrier();
        const char* sb = &S[rd][0];
        rd = (rd == 2) ? 0 : rd + 1;
        half8 a0 = *(const half8*)(sb + offA[0]);
        half8 a1 = *(const half8*)(sb + offA[1]);
        half8 a2 = *(const half8*)(sb + offA[2]);
        __builtin_amdgcn_s_setprio(1);
        #pragma unroll
        for (int n = 0; n < 6; ++n) {
            half8 bn = *(const half8*)(sb + offB[n]);
            acc[0][n] = __builtin_amdgcn_mfma_f32_16x16x32_f16(a0, bn, acc[0][n], 0, 0, 0);
            acc[1][n] = __builtin_amdgcn_mfma_f32_16x16x32_f16(a1, bn, acc[1][n], 0, 0, 0);
            acc[2][n] = __builtin_amdgcn_mfma_f32_16x16x32_f16(a2, bn, acc[2][n], 0, 0, 0);
        }
        __builtin_amdgcn_s_setprio(0);
        __builtin_amdgcn_s_barrier();
    }
#undef STG

    // epilogue: linearized chunk-major attn write
    const int col = lane & 15, rbase = (lane >> 4) * 4;
    #pragma unroll
    for (int m = 0; m < 3; ++m)
        #pragma unroll
        for (int n = 0; n < 6; ++n)
            #pragma unroll
            for (int rg = 0; rg < 4; ++rg) {
                int grow = ti * 192 + wr + m * 16 + rbase + rg;
                int gcol = tj * 192 + wc + n * 16 + col;
                attn[(((size_t)bz * 6 + (grow >> 7)) * NCP + (gcol >> 5)) * 4096
                     + (grow & 127) * 32 + (gcol & 31)] = acc[m][n][rg];
            }

    // per-(row, 96-col half) softmax partials; slot = tj*2 + (w&1).
    const int half = w & 1;
    #pragma unroll
    for (int m = 0; m < 3; ++m)
        #pragma unroll
        for (int rg = 0; rg < 4; ++rg) {
            float mx = -1e30f;
            #pragma unroll
            for (int n = 0; n < 6; ++n) mx = fmaxf(mx, acc[m][n][rg]);
            #pragma unroll
            for (int o = 1; o < 16; o <<= 1) mx = fmaxf(mx, __shfl_xor(mx, o));
            float s = 0.f;
            #pragma unroll
            for (int n = 0; n < 6; ++n) s += __expf(acc[m][n][rg] - mx);
            #pragma unroll
            for (int o = 1; o < 16; o <<= 1) s += __shfl_xor(s, o);
            if ((lane & 15) == 0) {
                int row = wr + m * 16 + (lane >> 4) * 4 + rg;
                part[((size_t)bz * C_ + ti * 192 + row) * 8 + tj * 2 + half] =
                    make_float2(mx, s);
            }
        }
}

// ---------------------------------------------------------------------------
// sm_combine: stats[R] = {m, gamma/s} from 8 per-(tile,half) partials per row.
// ---------------------------------------------------------------------------
__global__ __launch_bounds__(256) void sm_combine(const float2* __restrict__ part,
                                                  float2* __restrict__ stats,
                                                  const float* __restrict__ gamma,
                                                  int cur) {
    const int bid = blockIdx.x;
    const int bz = bid % cur, u = bid / cur;     // u in [0,3)
    const int R = bz * C_ + u * 256 + threadIdx.x;
    float2 p[8];
    #pragma unroll
    for (int i = 0; i < 8; ++i) p[i] = part[(size_t)R * 8 + i];
    float m = p[0].x;
    #pragma unroll
    for (int i = 1; i < 8; ++i) m = fmaxf(m, p[i].x);
    float s = 0.f;
    #pragma unroll
    for (int i = 0; i < 8; ++i) s += p[i].y * __expf(p[i].x - m);
    stats[R] = make_float2(m, gamma[0] / s);
}

// ---------------------------------------------------------------------------
// pv10: out = (gamma*P)@V + feat1, softmax fused into A-staging. Paired
// chunks (12 phases of 2), ring-4 of 20KB slots. SINGLE DELTA vs round-13:
// A-read from LINEARIZED attn -> fully sequential 16KB/chunk stream.
// Thread t owns row r0=t>>2, k-group g4=t&3 (8 cols): 2 f32x4 loads/chunk
// (same count as round 13 -> all VM() values unchanged), 1 half8 ds_write.
// ---------------------------------------------------------------------------
__global__ __launch_bounds__(512, 4) void pv10(const float* __restrict__ attn,
                                               const char* __restrict__ vt,
                                               const float2* __restrict__ stats,
                                               const float* __restrict__ f1,
                                               float* __restrict__ out,
                                               int b0, int cur) {
    __shared__ __align__(16) char S[4][20480];   // per slot: A 8KB | B 12KB
    const int wg = blockIdx.x;
    const int bz = wg % cur, u = wg / cur;       // u in [0,18)
    const int ti = u / 3, tj = u % 3;
    const int t = threadIdx.x, lane = t & 63, w = t >> 6;
    const int rsub = lane >> 2, cbb = (lane & 3) * 16;

    // ---- A staging: thread t owns row r0, k-group g4 (8 cols) per chunk ----
    const int r0 = t >> 2;            // row 0..127
    const int g4 = t & 3;             // 16B k-group within 32-col chunk
    const float* srcA = attn + (((size_t)bz * 6 + ti) * NCP) * 4096 + t * 8;
    const float2 ms0 = stats[bz * C_ + ti * 128 + r0];
    const int aw0 = r0 * 64 + ((g4 ^ ((r0 >> 1) & 3)) << 4);

    // ---- B staging (g2l): same per-wave assignment as round 13 ----
    const char* vbase = vt + ((size_t)(bz * 3 + tj) * NCP) * 12288;
    const char *pB0, *pB1;
    int ob0, ob1;
    if (w < 4) {
        pB0 = vbase + (32 * w + rsub) * 64 + cbb;          ob0 = 8192 + (32 * w) * 64;
        pB1 = vbase + (32 * w + 16 + rsub) * 64 + cbb;     ob1 = 8192 + (32 * w + 16) * 64;
    } else {
        pB0 = vbase + (128 + 16 * (w - 4) + rsub) * 64 + cbb;
        ob0 = 8192 + (128 + 16 * (w - 4)) * 64;
        pB1 = vbase; ob1 = 0;  // unused
    }

    const int wr = (w >> 2) * 64, wc = (w & 3) * 48;
    const int r16 = lane & 15, cg = lane >> 4;
    int offA[4], offB[3];
    #pragma unroll
    for (int m = 0; m < 4; ++m) {
        int ra = wr + m * 16 + r16;
        offA[m] = ra * 64 + ((cg ^ ((ra >> 1) & 3)) << 4);
    }
    #pragma unroll
    for (int n = 0; n < 3; ++n) {
        int rb = wc + n * 16 + r16;
        offB[n] = 8192 + rb * 64 + ((cg ^ ((rb >> 1) & 3)) << 4);
    }

    f32x4 acc[4][3] = {};
    f32x4 vaA0, vaA1;    // named set A (even chunk of pair)
    f32x4 vaB0, vaB1;    // named set B (odd  chunk of pair)

#define STG_B(SLOT) do {                                  \
        g2l16(pB0, &S[SLOT][0] + ob0); pB0 += 12288;      \
        if (w < 4) { g2l16(pB1, &S[SLOT][0] + ob1); pB1 += 12288; } \
    } while (0)
#define LD_A(V0, V1) do { V0 = *(const f32x4*)srcA; V1 = *(const f32x4*)(srcA + 4); \
                          srcA += 4096; } while (0)
#define WR_A(SLOT, V0, V1) do {                                        \
        half8 h_;                                                      \
        _Pragma("unroll")                                              \
        for (int e = 0; e < 4; ++e) {                                  \
            h_[e]     = (_Float16)(__expf(V0[e] - ms0.x) * ms0.y);     \
            h_[4 + e] = (_Float16)(__expf(V1[e] - ms0.x) * ms0.y);     \
        }                                                              \
        *(half8*)(&S[SLOT][0] + aw0) = h_;                             \
    } while (0)
#define MFMA_SLOT(SB) do {                                             \
        const char* sb_ = (SB);                                        \
        half8 a_[4], b_[3];                                            \
        _Pragma("unroll")                                              \
        for (int m = 0; m < 4; ++m) a_[m] = *(const half8*)(sb_ + offA[m]); \
        _Pragma("unroll")                                              \
        for (int n = 0; n < 3; ++n) b_[n] = *(const half8*)(sb_ + offB[n]); \
        _Pragma("unroll")                                              \
        for (int m = 0; m < 4; ++m)                                    \
            _Pragma("unroll")                                          \
            for (int n = 0; n < 3; ++n)                                \
                acc[m][n] = __builtin_amdgcn_mfma_f32_16x16x32_f16(a_[m], b_[n], acc[m][n], 0, 0, 0); \
    } while (0)

    // prologue: A(0)->slot0, A(1)->slot1; B(0)->slot0, B(1)->slot1;
    // preload A(2)->setA, A(3)->setB.
    LD_A(vaA0, vaA1);
    WR_A(0, vaA0, vaA1);
    LD_A(vaB0, vaB1);
    WR_A(1, vaB0, vaB1);
    STG_B(0); STG_B(1);
    LD_A(vaA0, vaA1);        // chunk 2
    LD_A(vaB0, vaB1);        // chunk 3

    for (int p = 0; p < 12; ++p) {
        const int sa = (2 * p) & 3;          // slot of chunk 2p
        asm volatile("s_waitcnt lgkmcnt(0)" ::: "memory");
        __builtin_amdgcn_s_barrier();
        if (p < 11) { STG_B((sa + 2) & 3); STG_B((sa + 3) & 3); }
        if (p < 11) { if (w < 4) VM(8); else VM(6); }
        else        { VM(0); }
        __builtin_amdgcn_s_barrier();

        __builtin_amdgcn_s_setprio(1);
        MFMA_SLOT(&S[sa][0]);
        MFMA_SLOT(&S[sa ^ 1][0]);            // slot of chunk 2p+1
        __builtin_amdgcn_s_setprio(0);

        if (p < 11) {
            WR_A((sa + 2) & 3, vaA0, vaA1);  // chunk 2p+2
            WR_A((sa + 3) & 3, vaB0, vaB1);  // chunk 2p+3
            if (p < 10) {
                LD_A(vaA0, vaA1);            // chunk 2p+4
                LD_A(vaB0, vaB1);            // chunk 2p+5
            }
        }
    }
#undef MFMA_SLOT
#undef WR_A
#undef LD_A
#undef STG_B

    const int b = b0 + bz;
    const float* f1b = f1 + ((size_t)b * C_ + ti * 128) * HW_ + tj * 192;
    float*       ob  = out + ((size_t)b * C_ + ti * 128) * HW_ + tj * 192;
    const int col = lane & 15, rbase = (lane >> 4) * 4;
    #pragma unroll
    for (int m = 0; m < 4; ++m)
        #pragma unroll
        for (int n = 0; n < 3; ++n)
            #pragma unroll
            for (int rg = 0; rg < 4; ++rg) {
                int r2 = wr + m * 16 + rbase + rg;
                int c2 = wc + n * 16 + col;
                ob[(size_t)r2 * HW_ + c2] = acc[m][n][rg] + f1b[(size_t)r2 * HW_ + c2];
            }
}

// ---------------------------------------------------------------------------
extern "C" void kernel_launch(void* const* d_in, const int* in_sizes, int n_in,
                              void* d_out, int out_size, void* d_ws, size_t ws_size,
                              hipStream_t stream) {
    const float* feat1 = (const float*)d_in[0];
    const float* feat2 = (const float*)d_in[1];
    const float* gamma = (const float*)d_in[2];
    float* out = (float*)d_out;

    const size_t SZ_Q    = (size_t)C_ * HW_ * 2;      //   884,736 B/batch
    const size_t SZ_ATTN = (size_t)C_ * C_  * 4;      // 2,359,296 B/batch (fp32)
    const size_t SZ_PART = (size_t)C_ * 8 * 8;        //    49,152 B/batch
    const size_t SZ_ST   = (size_t)C_ * 8;            //     6,144 B/batch
    const size_t per_batch = SZ_ATTN + 3 * SZ_Q + SZ_PART + SZ_ST;

    int nb = (int)(ws_size / per_batch);
    if (nb < 1) nb = 1;
    if (nb > B_) nb = B_;

    char* ws     = (char*)d_ws;
    float* attn  = (float*)ws;
    char* q16    = ws + (size_t)nb * SZ_ATTN;
    char* kv16   = q16 + (size_t)nb * SZ_Q;
    char* vtb    = kv16 + (size_t)nb * SZ_Q;
    float2* part = (float2*)(vtb + (size_t)nb * SZ_Q);
    float2* stats = (float2*)((char*)part + (size_t)nb * SZ_PART);

    for (int b0 = 0; b0 < B_; b0 += nb) {
        int cur = (B_ - b0 < nb) ? (B_ - b0) : nb;
        prep_all<<<cur * 288, 256, 0, stream>>>(feat1, feat2, q16, kv16, vtb, b0, cur, cur * 216);
        qk6<<<cur * 16, 512, 0, stream>>>(q16, kv16, attn, part, cur);
        sm_combine<<<cur * 3, 256, 0, stream>>>(part, stats, gamma, cur);
        pv10<<<cur * 18, 512, 0, stream>>>(attn, vtb, stats, feat1, out, b0, cur);
    }
}

// Round 16
// 142.527 us; speedup vs baseline: 1.2418x; 1.0015x over previous
//
#include <hip/hip_runtime.h>

// Problem constants: B=32, C=768, H=W=24 -> HW=576
#define B_  32
#define C_  768
#define HW_ 576

#define NCQ 18               // HW_/32 k-chunks (qk)
#define NCP 24               // C_/32 k-chunks (pv)

typedef _Float16 half8 __attribute__((ext_vector_type(8)));
typedef _Float16 half4 __attribute__((ext_vector_type(4)));
typedef float    f32x4 __attribute__((ext_vector_type(4)));

__device__ __forceinline__ void g2l16(const void* g, void* l) {
    __builtin_amdgcn_global_load_lds(
        (const __attribute__((address_space(1))) unsigned int*)g,
        (__attribute__((address_space(3))) unsigned int*)l, 16, 0, 0);
}

#define VM(N) asm volatile("s_waitcnt vmcnt(" #N ")" ::: "memory")

// attn is stored LINEARIZED chunk-major (pv's staging layout):
//   float index = ((bz*6 + strip)*24 + chunk)*4096 + row_in_strip*32 + col_in_chunk
// making pv's A-read a fully sequential 16KB-per-chunk stream.

// ---------------------------------------------------------------------------
// prep_all: feat1/feat2 fp32 -> q16/kv16 (row-major fp16 staged tiles) and
// vt (transposed fp16 tiles via coalesced LDS transpose).
// ---------------------------------------------------------------------------
__global__ __launch_bounds__(256) void prep_all(const float* __restrict__ f1,
                                                const float* __restrict__ f2,
                                                char* __restrict__ q16,
                                                char* __restrict__ kv16,
                                                char* __restrict__ vt,
                                                int b0, int cur, int nqk) {
    __shared__ float Vsh[32 * 201];
    const int bid = blockIdx.x;
    if (bid < nqk) {
        const int bz = bid % cur, u = bid / cur;        // u in [0,216)
        int g   = u * 256 + threadIdx.x;                // [ti][k0][row][x]
        int x   = g & 3;
        int row = (g >> 2) & 127;
        int t3  = g >> 9;                               // ti*18 + k0
        int k0  = t3 % 18;
        int ti  = t3 / 18;
        int kc  = x ^ ((row >> 1) & 3);
        size_t src = ((size_t)(b0 + bz) * C_ + ti * 128 + row) * HW_ + k0 * 32 + kc * 8;
        f32x4 a0 = *(const f32x4*)(f1 + src);
        f32x4 a1 = *(const f32x4*)(f1 + src + 4);
        f32x4 c0 = *(const f32x4*)(f2 + src);
        f32x4 c1 = *(const f32x4*)(f2 + src + 4);
        half8 ha, hb;
        #pragma unroll
        for (int e = 0; e < 4; ++e) {
            ha[e] = (_Float16)a0[e]; ha[4 + e] = (_Float16)a1[e];
            hb[e] = (_Float16)c0[e]; hb[4 + e] = (_Float16)c1[e];
        }
        size_t dst = ((size_t)(((size_t)bz * 6 + ti) * 18 + k0) << 9) | (g & 511);
        *(half8*)(q16  + dst * 16) = ha;
        *(half8*)(kv16 + dst * 16) = hb;
    } else {
        int bid2 = bid - nqk;
        const int bz = bid2 % cur, u = bid2 / cur;      // u in [0,72)
        int k0 = u / 3, tj = u % 3;
        int b  = b0 + bz;
        int t  = threadIdx.x;
        #pragma unroll
        for (int p = 0; p < 6; ++p) {
            int fidx = p * 256 + t;
            int dd = fidx / 48, c4 = fidx % 48;
            f32x4 v = *(const f32x4*)(f2 + ((size_t)b * C_ + k0 * 32 + dd) * HW_ + tj * 192 + c4 * 4);
            #pragma unroll
            for (int e = 0; e < 4; ++e) Vsh[dd * 201 + c4 * 4 + e] = v[e];
        }
        __syncthreads();
        char* ob = vt + ((size_t)(bz * 3 + tj) * NCP + k0) * 12288;
        #pragma unroll
        for (int p = 0; p < 3; ++p) {
            int o = p * 256 + t;
            int x = o & 3, n = o >> 2;
            int kc = x ^ ((n >> 1) & 3);
            half8 h;
            #pragma unroll
            for (int j = 0; j < 8; ++j) h[j] = (_Float16)Vsh[(kc * 8 + j) * 201 + n];
            *(half8*)(ob + o * 16) = h;
        }
    }
}

// ---------------------------------------------------------------------------
// qk6: attn = q @ kv^T. Tile 192x192, 8 waves (4Mx2N), BK=32, ring-3,
// depth-2 counted-vmcnt pipeline. Epilogue: linearized chunk-major attn
// write + fp32 softmax partials (8 race-free slots per row).
// ---------------------------------------------------------------------------
__global__ __launch_bounds__(512, 4) void qk6(const char* __restrict__ q16,
                                              const char* __restrict__ kv16,
                                              float* __restrict__ attn,
                                              float2* __restrict__ part,
                                              int cur) {
    __shared__ __align__(16) char S[3][24576];
    const int wg = blockIdx.x;
    const int bz = wg % cur, u = wg / cur;   // u in [0,16)
    const int ti = u >> 2, tj = u & 3;
    const int t = threadIdx.x, lane = t & 63, w = t >> 6;
    const int rsub = lane >> 2, cb = (lane & 3) * 16;

    const char *p0, *p1, *p2;
    int o0, o1, o2;
    {
        auto arow = [&](int l) {
            int gr = ti * 192 + 16 * l + rsub;
            return q16 + ((size_t)(bz * 6 + (gr >> 7)) * NCQ) * 8192 + (gr & 127) * 64 + cb;
        };
        auto brow = [&](int l) {
            int gd = tj * 192 + 16 * l + rsub;
            return kv16 + ((size_t)(bz * 6 + (gd >> 7)) * NCQ) * 8192 + (gd & 127) * 64 + cb;
        };
        if (w < 4) {
            p0 = arow(2 * w);     o0 = (2 * w) * 1024;
            p1 = arow(2 * w + 1); o1 = (2 * w + 1) * 1024;
            p2 = brow(8 + w);     o2 = 12288 + (8 + w) * 1024;
        } else {
            int v = w - 4;
            p0 = brow(2 * v);     o0 = 12288 + (2 * v) * 1024;
            p1 = brow(2 * v + 1); o1 = 12288 + (2 * v + 1) * 1024;
            p2 = arow(8 + v);     o2 = (8 + v) * 1024;
        }
    }

    const int wr = (w >> 1) * 48, wc = (w & 1) * 96;
    const int r16 = lane & 15, cg = lane >> 4;
    int offA[3], offB[6];
    #pragma unroll
    for (int m = 0; m < 3; ++m) {
        int ra = wr + m * 16 + r16;
        offA[m] = ra * 64 + ((cg ^ ((ra >> 1) & 3)) << 4);
    }
    #pragma unroll
    for (int n = 0; n < 6; ++n) {
        int rb = wc + n * 16 + r16;
        offB[n] = 12288 + rb * 64 + ((cg ^ ((rb >> 1) & 3)) << 4);
    }

    f32x4 acc[3][6] = {};

#define STG(SLOT) do {                          \
        char* sb_ = &S[SLOT][0];                \
        g2l16(p0, sb_ + o0);                    \
        g2l16(p1, sb_ + o1);                    \
        g2l16(p2, sb_ + o2);                    \
        p0 += 8192; p1 += 8192; p2 += 8192;     \
    } while (0)

    STG(0); STG(1);
    int rd = 0, st = 2;
    for (int c = 0; c < NCQ; ++c) {
        if (c + 2 < NCQ) {
            STG(st); st = (st == 2) ? 0 : st + 1;
            VM(6);
        } else if (c + 2 == NCQ) {
            VM(3);
        } else {
            VM(0);
        }
        __builtin_amdgcn_s_barrier();
        const char* sb = &S[rd][0];
        rd = (rd == 2) ? 0 : rd + 1;
        half8 a0 = *(const half8*)(sb + offA[0]);
        half8 a1 = *(const half8*)(sb + offA[1]);
        half8 a2 = *(const half8*)(sb + offA[2]);
        __builtin_amdgcn_s_setprio(1);
        #pragma unroll
        for (int n = 0; n < 6; ++n) {
            half8 bn = *(const half8*)(sb + offB[n]);
            acc[0][n] = __builtin_amdgcn_mfma_f32_16x16x32_f16(a0, bn, acc[0][n], 0, 0, 0);
            acc[1][n] = __builtin_amdgcn_mfma_f32_16x16x32_f16(a1, bn, acc[1][n], 0, 0, 0);
            acc[2][n] = __builtin_amdgcn_mfma_f32_16x16x32_f16(a2, bn, acc[2][n], 0, 0, 0);
        }
        __builtin_amdgcn_s_setprio(0);
        __builtin_amdgcn_s_barrier();
    }
#undef STG

    // epilogue: linearized chunk-major attn write
    const int col = lane & 15, rbase = (lane >> 4) * 4;
    #pragma unroll
    for (int m = 0; m < 3; ++m)
        #pragma unroll
        for (int n = 0; n < 6; ++n)
            #pragma unroll
            for (int rg = 0; rg < 4; ++rg) {
                int grow = ti * 192 + wr + m * 16 + rbase + rg;
                int gcol = tj * 192 + wc + n * 16 + col;
                attn[(((size_t)bz * 6 + (grow >> 7)) * NCP + (gcol >> 5)) * 4096
                     + (grow & 127) * 32 + (gcol & 31)] = acc[m][n][rg];
            }

    // per-(row, 96-col half) softmax partials; slot = tj*2 + (w&1).
    const int half = w & 1;
    #pragma unroll
    for (int m = 0; m < 3; ++m)
        #pragma unroll
        for (int rg = 0; rg < 4; ++rg) {
            float mx = -1e30f;
            #pragma unroll
            for (int n = 0; n < 6; ++n) mx = fmaxf(mx, acc[m][n][rg]);
            #pragma unroll
            for (int o = 1; o < 16; o <<= 1) mx = fmaxf(mx, __shfl_xor(mx, o));
            float s = 0.f;
            #pragma unroll
            for (int n = 0; n < 6; ++n) s += __expf(acc[m][n][rg] - mx);
            #pragma unroll
            for (int o = 1; o < 16; o <<= 1) s += __shfl_xor(s, o);
            if ((lane & 15) == 0) {
                int row = wr + m * 16 + (lane >> 4) * 4 + rg;
                part[((size_t)bz * C_ + ti * 192 + row) * 8 + tj * 2 + half] =
                    make_float2(mx, s);
            }
        }
}

// ---------------------------------------------------------------------------
// pv10: out = (gamma*P)@V + feat1, softmax fused into A-staging. Paired
// chunks (12 phases of 2), ring-4 of 20KB slots, linearized attn A-stream.
// sm_combine FOLDED into the preamble: each thread reduces its row's 8
// partials (identical order as the old kernel -> bit-identical stats).
// out written with nontemporal stores (never re-read; saves L2/L3 room).
// ---------------------------------------------------------------------------
__global__ __launch_bounds__(512, 4) void pv10(const float* __restrict__ attn,
                                               const char* __restrict__ vt,
                                               const float2* __restrict__ part,
                                               const float* __restrict__ gamma,
                                               const float* __restrict__ f1,
                                               float* __restrict__ out,
                                               int b0, int cur) {
    __shared__ __align__(16) char S[4][20480];   // per slot: A 8KB | B 12KB
    const int wg = blockIdx.x;
    const int bz = wg % cur, u = wg / cur;       // u in [0,18)
    const int ti = u / 3, tj = u % 3;
    const int t = threadIdx.x, lane = t & 63, w = t >> 6;
    const int rsub = lane >> 2, cbb = (lane & 3) * 16;

    // ---- A staging: thread t owns row r0, k-group g4 (8 cols) per chunk ----
    const int r0 = t >> 2;            // row 0..127
    const int g4 = t & 3;             // 16B k-group within 32-col chunk
    const float* srcA = attn + (((size_t)bz * 6 + ti) * NCP) * 4096 + t * 8;
    const int aw0 = r0 * 64 + ((g4 ^ ((r0 >> 1) & 3)) << 4);

    // ---- stats: fold sm_combine (identical reduction order) ----
    float2 ms0;
    {
        const float2* pr = part + ((size_t)bz * C_ + ti * 128 + r0) * 8;
        float2 p8[8];
        #pragma unroll
        for (int i = 0; i < 8; ++i) p8[i] = pr[i];
        float m = p8[0].x;
        #pragma unroll
        for (int i = 1; i < 8; ++i) m = fmaxf(m, p8[i].x);
        float s = 0.f;
        #pragma unroll
        for (int i = 0; i < 8; ++i) s += p8[i].y * __expf(p8[i].x - m);
        ms0 = make_float2(m, gamma[0] / s);
    }

    // ---- B staging (g2l) ----
    const char* vbase = vt + ((size_t)(bz * 3 + tj) * NCP) * 12288;
    const char *pB0, *pB1;
    int ob0, ob1;
    if (w < 4) {
        pB0 = vbase + (32 * w + rsub) * 64 + cbb;          ob0 = 8192 + (32 * w) * 64;
        pB1 = vbase + (32 * w + 16 + rsub) * 64 + cbb;     ob1 = 8192 + (32 * w + 16) * 64;
    } else {
        pB0 = vbase + (128 + 16 * (w - 4) + rsub) * 64 + cbb;
        ob0 = 8192 + (128 + 16 * (w - 4)) * 64;
        pB1 = vbase; ob1 = 0;  // unused
    }

    const int wr = (w >> 2) * 64, wc = (w & 3) * 48;
    const int r16 = lane & 15, cg = lane >> 4;
    int offA[4], offB[3];
    #pragma unroll
    for (int m = 0; m < 4; ++m) {
        int ra = wr + m * 16 + r16;
        offA[m] = ra * 64 + ((cg ^ ((ra >> 1) & 3)) << 4);
    }
    #pragma unroll
    for (int n = 0; n < 3; ++n) {
        int rb = wc + n * 16 + r16;
        offB[n] = 8192 + rb * 64 + ((cg ^ ((rb >> 1) & 3)) << 4);
    }

    f32x4 acc[4][3] = {};
    f32x4 vaA0, vaA1;    // named set A (even chunk of pair)
    f32x4 vaB0, vaB1;    // named set B (odd  chunk of pair)

#define STG_B(SLOT) do {                                  \
        g2l16(pB0, &S[SLOT][0] + ob0); pB0 += 12288;      \
        if (w < 4) { g2l16(pB1, &S[SLOT][0] + ob1); pB1 += 12288; } \
    } while (0)
#define LD_A(V0, V1) do { V0 = *(const f32x4*)srcA; V1 = *(const f32x4*)(srcA + 4); \
                          srcA += 4096; } while (0)
#define WR_A(SLOT, V0, V1) do {                                        \
        half8 h_;                                                      \
        _Pragma("unroll")                                              \
        for (int e = 0; e < 4; ++e) {                                  \
            h_[e]     = (_Float16)(__expf(V0[e] - ms0.x) * ms0.y);     \
            h_[4 + e] = (_Float16)(__expf(V1[e] - ms0.x) * ms0.y);     \
        }                                                              \
        *(half8*)(&S[SLOT][0] + aw0) = h_;                             \
    } while (0)
#define MFMA_SLOT(SB) do {                                             \
        const char* sb_ = (SB);                                        \
        half8 a_[4], b_[3];                                            \
        _Pragma("unroll")                                              \
        for (int m = 0; m < 4; ++m) a_[m] = *(const half8*)(sb_ + offA[m]); \
        _Pragma("unroll")                                              \
        for (int n = 0; n < 3; ++n) b_[n] = *(const half8*)(sb_ + offB[n]); \
        _Pragma("unroll")                                              \
        for (int m = 0; m < 4; ++m)                                    \
            _Pragma("unroll")                                          \
            for (int n = 0; n < 3; ++n)                                \
                acc[m][n] = __builtin_amdgcn_mfma_f32_16x16x32_f16(a_[m], b_[n], acc[m][n], 0, 0, 0); \
    } while (0)

    // prologue: A(0)->slot0, A(1)->slot1; B(0)->slot0, B(1)->slot1;
    // preload A(2)->setA, A(3)->setB.
    LD_A(vaA0, vaA1);
    WR_A(0, vaA0, vaA1);
    LD_A(vaB0, vaB1);
    WR_A(1, vaB0, vaB1);
    STG_B(0); STG_B(1);
    LD_A(vaA0, vaA1);        // chunk 2
    LD_A(vaB0, vaB1);        // chunk 3

    for (int p = 0; p < 12; ++p) {
        const int sa = (2 * p) & 3;          // slot of chunk 2p
        asm volatile("s_waitcnt lgkmcnt(0)" ::: "memory");
        __builtin_amdgcn_s_barrier();
        if (p < 11) { STG_B((sa + 2) & 3); STG_B((sa + 3) & 3); }
        if (p < 11) { if (w < 4) VM(8); else VM(6); }
        else        { VM(0); }
        __builtin_amdgcn_s_barrier();

        __builtin_amdgcn_s_setprio(1);
        MFMA_SLOT(&S[sa][0]);
        MFMA_SLOT(&S[sa ^ 1][0]);            // slot of chunk 2p+1
        __builtin_amdgcn_s_setprio(0);

        if (p < 11) {
            WR_A((sa + 2) & 3, vaA0, vaA1);  // chunk 2p+2
            WR_A((sa + 3) & 3, vaB0, vaB1);  // chunk 2p+3
            if (p < 10) {
                LD_A(vaA0, vaA1);            // chunk 2p+4
                LD_A(vaB0, vaB1);            // chunk 2p+5
            }
        }
    }
#undef MFMA_SLOT
#undef WR_A
#undef LD_A
#undef STG_B

    const int b = b0 + bz;
    const float* f1b = f1 + ((size_t)b * C_ + ti * 128) * HW_ + tj * 192;
    float*       ob  = out + ((size_t)b * C_ + ti * 128) * HW_ + tj * 192;
    const int col = lane & 15, rbase = (lane >> 4) * 4;
    #pragma unroll
    for (int m = 0; m < 4; ++m)
        #pragma unroll
        for (int n = 0; n < 3; ++n)
            #pragma unroll
            for (int rg = 0; rg < 4; ++rg) {
                int r2 = wr + m * 16 + rbase + rg;
                int c2 = wc + n * 16 + col;
                float v = acc[m][n][rg] + f1b[(size_t)r2 * HW_ + c2];
                __builtin_nontemporal_store(v, &ob[(size_t)r2 * HW_ + c2]);
            }
}

// ---------------------------------------------------------------------------
extern "C" void kernel_launch(void* const* d_in, const int* in_sizes, int n_in,
                              void* d_out, int out_size, void* d_ws, size_t ws_size,
                              hipStream_t stream) {
    const float* feat1 = (const float*)d_in[0];
    const float* feat2 = (const float*)d_in[1];
    const float* gamma = (const float*)d_in[2];
    float* out = (float*)d_out;

    const size_t SZ_Q    = (size_t)C_ * HW_ * 2;      //   884,736 B/batch
    const size_t SZ_ATTN = (size_t)C_ * C_  * 4;      // 2,359,296 B/batch (fp32)
    const size_t SZ_PART = (size_t)C_ * 8 * 8;        //    49,152 B/batch
    const size_t per_batch = SZ_ATTN + 3 * SZ_Q + SZ_PART;

    int nb = (int)(ws_size / per_batch);
    if (nb < 1) nb = 1;
    if (nb > B_) nb = B_;

    char* ws     = (char*)d_ws;
    float* attn  = (float*)ws;
    char* q16    = ws + (size_t)nb * SZ_ATTN;
    char* kv16   = q16 + (size_t)nb * SZ_Q;
    char* vtb    = kv16 + (size_t)nb * SZ_Q;
    float2* part = (float2*)(vtb + (size_t)nb * SZ_Q);

    for (int b0 = 0; b0 < B_; b0 += nb) {
        int cur = (B_ - b0 < nb) ? (B_ - b0) : nb;
        prep_all<<<cur * 288, 256, 0, stream>>>(feat1, feat2, q16, kv16, vtb, b0, cur, cur * 216);
        qk6<<<cur * 16, 512, 0, stream>>>(q16, kv16, attn, part, cur);
        pv10<<<cur * 18, 512, 0, stream>>>(attn, vtb, part, gamma, feat1, out, b0, cur);
    }
}